// Round 8
// baseline (67.737 us; speedup 1.0000x reference)
//
#include <hip/hip_runtime.h>
#include <hip/hip_fp16.h>

#define NB    8
#define NDET  128
#define NT    2048
#define NPIX  65536            // 256*256
#define NELEM (NDET * NT)      // 262144 per batch
#define NGRP  32               // detector groups of 4

// ws layout (bytes):
//   0       : double partials [256][2]  (sum, sumsq per reduction block)
//   4096    : float  wsf[0..7] mean, [8..15] inv_std, uint [16] valid-mode,
//             [17] 1/norm, [32..159] apodn[d]
//   8192    : __half S16[NDET][NT][NB]  (4 MiB)
//   +4M     : 32 MiB region shared in-place:
//               k_pack writes packT[g][p] uint4 (4B/det: k0|valid<<11|fp16alpha<<16)
//               k_das7 reads packT[g][p], overwrites same slot with fp16 partials
//               k_reduce2 reads it as __half pT[g][p][8]
//             (das2 fallback reuses this region as float partials[8][NB][NPIX])

#define WS_S16_OFF   8192
#define WS_PT_OFF    (8192 + (size_t)NDET * NT * NB * 2)
#define WS7_REQUIRED (WS_PT_OFF + (size_t)NGRP * NPIX * NB * 2)
#define WS2_REQUIRED (WS_PT_OFF + (size_t)8 * NB * NPIX * 4)

__global__ __launch_bounds__(256) void k_stats(const float* __restrict__ sino,
                                               double* __restrict__ wsd) {
    const int bx = blockIdx.x;            // 0..255
    const int b = bx >> 5, i = bx & 31;   // batch, chunk
    const float4* src = (const float4*)(sino + (size_t)b * NELEM);
    const int base = i * 2048;            // 2048 float4 per chunk
    double s = 0.0, ss = 0.0;
    for (int r = 0; r < 8; ++r) {
        float4 v = src[base + r * 256 + threadIdx.x];
        double d0 = v.x, d1 = v.y, d2 = v.z, d3 = v.w;
        s  += d0 + d1 + d2 + d3;
        ss += d0 * d0 + d1 * d1 + d2 * d2 + d3 * d3;
    }
    for (int off = 32; off; off >>= 1) {
        s  += __shfl_down(s, off);
        ss += __shfl_down(ss, off);
    }
    __shared__ double lds[8];
    const int wave = threadIdx.x >> 6;
    if ((threadIdx.x & 63) == 0) { lds[wave * 2] = s; lds[wave * 2 + 1] = ss; }
    __syncthreads();
    if (threadIdx.x == 0) {
        double S = 0, SS = 0;
        for (int w = 0; w < 4; ++w) { S += lds[w * 2]; SS += lds[w * 2 + 1]; }
        wsd[bx * 2] = S; wsd[bx * 2 + 1] = SS;
    }
}

__global__ __launch_bounds__(256) void k_finalize(const float* __restrict__ apod,
                                                  const unsigned char* __restrict__ validb,
                                                  const double* __restrict__ wsd,
                                                  float* __restrict__ wsf) {
    __shared__ float sap[NDET];
    __shared__ int sflag;
    const int t = threadIdx.x;
    if (t == 0) sflag = 0;
    if (t < NDET) sap[t] = apod[t];
    // Detect `valid` element width. numpy bool -> 1 byte/elem: bytes at
    // offset%4==1 are ~99% ones somewhere in 64KB. int32/f32: always 0.
    int local = 0;
    {
        const unsigned char* vb = validb + t * 256;
        for (int j = 1; j < 256; j += 4) local |= (vb[j] != 0);
    }
    __syncthreads();
    if (local) atomicOr(&sflag, 1);
    if (t < NB) {
        double S = 0, SS = 0;
        for (int i = 0; i < 32; ++i) {
            S  += wsd[(t * 32 + i) * 2];
            SS += wsd[(t * 32 + i) * 2 + 1];
        }
        double mean = S / (double)NELEM;
        double var  = SS / (double)NELEM - mean * mean;
        double istd = 1.0 / sqrt(var + (double)(1.1920928955078125e-07f));
        wsf[t]     = (float)mean;
        wsf[8 + t] = (float)istd;
    }
    if (t == 0) {
        double a = 0;
        for (int d = 0; d < NDET; ++d) a += (double)sap[d];
        float norm = fmaxf((float)a, 1.1754943508222875e-38f);
        wsf[17] = 1.0f / norm;
    }
    __syncthreads();
    if (t < NDET) wsf[32 + t] = sap[t] * wsf[17];
    if (t == 0) ((unsigned int*)wsf)[16] = (unsigned int)(sflag != 0);
}

__global__ __launch_bounds__(256) void k_build(const float* __restrict__ sino,
                                               const float* __restrict__ wsf,
                                               __half* __restrict__ S16) {
    const int dt = blockIdx.x * 256 + threadIdx.x;   // d*NT + t
    union { uint4 q; __half h[8]; } u;
#pragma unroll
    for (int b = 0; b < NB; ++b) {
        float x = sino[(size_t)b * NELEM + dt];
        u.h[b] = __float2half((x - wsf[b]) * wsf[8 + b]);
    }
    *(uint4*)(S16 + (size_t)dt * 8) = u.q;
}

// ---- pack v2: no LDS, no barrier. Thread (g = tid&31, pl = tid>>5).
// Reads: lanes 0-31 cover one 512B pixel-row contiguously (int4/float4/valid
// all coalesced, 4 lines/wave-instr). Writes: packT[g][p] 16B/lane, 32-way
// 1MB-strided scatter — posted stores, merged to full lines in L2 (each block
// leaves 512B-contiguous runs per g). 2048 blocks, 4 indep iters/thread.
// word = (k0 & 0x7FF) | (valid << 11) | (fp16(alpha) << 16)
__global__ __launch_bounds__(256) void k_pack(const int* __restrict__ k0,
                                              const float* __restrict__ alpha,
                                              const void* __restrict__ valid,
                                              const float* __restrict__ wsf,
                                              uint4* __restrict__ packT) {
    const unsigned int mode = ((const unsigned int*)wsf)[16];
    const int g  = threadIdx.x & 31;
    const int pl = threadIdx.x >> 5;          // 0..7
    const int pbase = blockIdx.x * 32;        // 2048 blocks x 32 px
#pragma unroll
    for (int r = 0; r < 4; ++r) {
        const int p = pbase + r * 8 + pl;
        const size_t e = (size_t)p * NDET + g * 4;
        int4   kq = *(const int4*)(k0 + e);
        float4 aq = *(const float4*)(alpha + e);
        unsigned int vb[4];
        if (mode) {
            unsigned int v = *(const unsigned int*)((const unsigned char*)valid + e);
            vb[0] = v & 0xffu; vb[1] = (v >> 8) & 0xffu;
            vb[2] = (v >> 16) & 0xffu; vb[3] = v >> 24;
        } else {
            uint4 v = *(const uint4*)((const unsigned int*)valid + e);
            vb[0] = v.x; vb[1] = v.y; vb[2] = v.z; vb[3] = v.w;
        }
        const int   ks[4] = {kq.x, kq.y, kq.z, kq.w};
        const float as[4] = {aq.x, aq.y, aq.z, aq.w};
        uint4 o;
        unsigned int* ow = (unsigned int*)&o;
#pragma unroll
        for (int j = 0; j < 4; ++j) {
            __half ha = __float2half_rn(as[j]);
            unsigned short hb = *(unsigned short*)&ha;
            ow[j] = ((unsigned int)ks[j] & 0x7FFu) | ((vb[j] ? 1u : 0u) << 11) |
                    ((unsigned int)hb << 16);
        }
        packT[(size_t)g * NPIX + p] = o;
    }
}

__device__ __forceinline__ float2 h2f(unsigned int w) {
    __half2 h;
    *reinterpret_cast<unsigned int*>(&h) = w;
    return __half22float2(h);
}

// ---- LDS-staged DAS v7: lane = pixel, packed coalesced LUT, in-place pT.
// XCD-aligned: x = blockIdx&7, g = x*4+sub. Per lane per iter: ONE coalesced
// uint4 load from pk[g][p], 8 ds_read_b128 gathers, in-lane det sum, then
// OVERWRITE pk[g][p] with the fp16 partials (same thread/addr: RAW then WAR).
__global__ __launch_bounds__(1024) void k_das7(uint4* pk,            // no restrict: aliased read/write
                                               const __half* __restrict__ S16,
                                               const float* __restrict__ wsf) {
    __shared__ __align__(16) __half SL[4 * NT * NB];   // 128 KiB
    const int x     = blockIdx.x & 7;
    const int sub   = (blockIdx.x >> 3) & 3;
    const int chunk = blockIdx.x >> 5;                 // 0..7
    const int g     = x * 4 + sub;                     // 0..31
    {
        const uint4* src = (const uint4*)(S16 + (size_t)g * 4 * NT * NB);
        uint4* dst = (uint4*)SL;
#pragma unroll
        for (int i = 0; i < 8; ++i)
            dst[i * 1024 + threadIdx.x] = src[i * 1024 + threadIdx.x];
    }
    __syncthreads();

    float apn[4];
#pragma unroll
    for (int j = 0; j < 4; ++j) apn[j] = wsf[32 + g * 4 + j];

    const int p0 = chunk * 8192 + (int)threadIdx.x;
    const size_t base = (size_t)g * NPIX + p0;         // uint4 index

    uint4 pkb = pk[base];                              // iter-0 prefetch
    for (int it = 0; it < 8; ++it) {
        const uint4 pkc = pkb;
        if (it < 7) pkb = pk[base + (size_t)(it + 1) * 1024];

        const unsigned int pw[4] = {pkc.x, pkc.y, pkc.z, pkc.w};
        float acc[NB] = {0.f, 0.f, 0.f, 0.f, 0.f, 0.f, 0.f, 0.f};
#pragma unroll
        for (int j = 0; j < 4; ++j) {
            const unsigned int wj = pw[j];
            const int kk = (int)(wj & 0x7FFu);
            unsigned short hb = (unsigned short)(wj >> 16);
            const float aa = __half2float(*(const __half*)&hb);
            const float w  = (wj & 0x800u) ? apn[j] : 0.0f;
            const float wb = w * aa;
            const float wa = w - wb;
            const uint4* s = (const uint4*)(SL + ((size_t)(j * NT + kk) << 3));
            uint4 q0 = s[0];   // tap k,   8 batches
            uint4 q1 = s[1];   // tap k+1, 8 batches
            const unsigned int w0[4] = {q0.x, q0.y, q0.z, q0.w};
            const unsigned int w1[4] = {q1.x, q1.y, q1.z, q1.w};
#pragma unroll
            for (int h = 0; h < 4; ++h) {
                float2 f0 = h2f(w0[h]);
                float2 f1 = h2f(w1[h]);
                acc[2 * h]     += wa * f0.x + wb * f1.x;
                acc[2 * h + 1] += wa * f0.y + wb * f1.y;
            }
        }
        union { uint4 q; __half2 h[4]; } o;
#pragma unroll
        for (int h = 0; h < 4; ++h)
            o.h[h] = __floats2half2_rn(acc[2 * h], acc[2 * h + 1]);
        pk[base + (size_t)it * 1024] = o.q;            // overwrite own slot
    }
}

__global__ __launch_bounds__(256) void k_reduce2(const __half* __restrict__ pT,
                                                 float* __restrict__ out) {
    const int p = blockIdx.x * 256 + threadIdx.x;
    float acc[NB] = {0.f, 0.f, 0.f, 0.f, 0.f, 0.f, 0.f, 0.f};
#pragma unroll
    for (int g = 0; g < NGRP; ++g) {
        union { uint4 q; __half2 h[4]; } u;
        u.q = *(const uint4*)(pT + ((size_t)g * NPIX + p) * NB);
#pragma unroll
        for (int h = 0; h < 4; ++h) {
            float2 f = __half22float2(u.h[h]);
            acc[2 * h]     += f.x;
            acc[2 * h + 1] += f.y;
        }
    }
#pragma unroll
    for (int b = 0; b < NB; ++b)
        out[(size_t)b * NPIX + p] = acc[b];
}

// ---- fallback: XCD-sliced L2-gather DAS (round-2 kernel) ----
__global__ __launch_bounds__(1024) void k_das2(const int* __restrict__ k0,
                                               const float* __restrict__ alpha,
                                               const void* __restrict__ valid,
                                               const __half* __restrict__ S16,
                                               const float* __restrict__ wsf,
                                               float* __restrict__ partials) {
    const int px = threadIdx.x & 255;
    const int dc = threadIdx.x >> 8;
    const int slice = blockIdx.x & 7;
    const int chunk = blockIdx.x >> 3;
    const int p  = chunk * 256 + px;
    const int d0 = slice * 16 + dc * 4;
    const unsigned int mode = ((const unsigned int*)wsf)[16];
    const float* apodn = wsf + 32;

    float acc[NB] = {0.f, 0.f, 0.f, 0.f, 0.f, 0.f, 0.f, 0.f};
    const size_t lbase = (size_t)p * NDET + d0;

    int4   k4 = *(const int4*)(k0 + lbase);
    float4 a4 = *(const float4*)(alpha + lbase);
    unsigned int vbits;
    if (mode) {
        unsigned int v4 = *(const unsigned int*)((const unsigned char*)valid + lbase);
        vbits = ((v4 & 0xffu) ? 1u : 0u) | (((v4 >> 8) & 0xffu) ? 2u : 0u) |
                (((v4 >> 16) & 0xffu) ? 4u : 0u) | ((v4 >> 24) ? 8u : 0u);
    } else {
        uint4 v4 = *(const uint4*)((const unsigned int*)valid + lbase);
        vbits = (v4.x ? 1u : 0u) | (v4.y ? 2u : 0u) | (v4.z ? 4u : 0u) | (v4.w ? 8u : 0u);
    }
    const int   kk[4] = {k4.x, k4.y, k4.z, k4.w};
    const float aa[4] = {a4.x, a4.y, a4.z, a4.w};
#pragma unroll
    for (int j = 0; j < 4; ++j) {
        const int d = d0 + j;
        const float w  = ((vbits >> j) & 1u) ? apodn[d] : 0.0f;
        const float wb = w * aa[j];
        const float wa = w - wb;
        const uint4* s = (const uint4*)(S16 + ((size_t)(d * NT + kk[j]) << 3));
        uint4 q0 = s[0];
        uint4 q1 = s[1];
        const unsigned int w0[4] = {q0.x, q0.y, q0.z, q0.w};
        const unsigned int w1[4] = {q1.x, q1.y, q1.z, q1.w};
#pragma unroll
        for (int h = 0; h < 4; ++h) {
            float2 f0 = h2f(w0[h]);
            float2 f1 = h2f(w1[h]);
            acc[2 * h]     += wa * f0.x + wb * f1.x;
            acc[2 * h + 1] += wa * f0.y + wb * f1.y;
        }
    }

    __shared__ float red[1024][9];
#pragma unroll
    for (int b = 0; b < NB; ++b) red[threadIdx.x][b] = acc[b];
    __syncthreads();
    if (dc == 0) {
#pragma unroll
        for (int b = 0; b < NB; ++b) {
            float v = red[px][b] + red[px + 256][b] + red[px + 512][b] + red[px + 768][b];
            partials[((size_t)slice * NB + b) * NPIX + p] = v;
        }
    }
}

__global__ __launch_bounds__(256) void k_reduce(const float* __restrict__ partials,
                                                float* __restrict__ out) {
    const int i = (blockIdx.x * 256 + threadIdx.x) * 4;
    float4 s = {0.f, 0.f, 0.f, 0.f};
#pragma unroll
    for (int g = 0; g < 8; ++g) {
        float4 v = *(const float4*)(partials + (size_t)g * NB * NPIX + i);
        s.x += v.x; s.y += v.y; s.z += v.z; s.w += v.w;
    }
    *(float4*)(out + i) = s;
}

extern "C" void kernel_launch(void* const* d_in, const int* in_sizes, int n_in,
                              void* d_out, int out_size, void* d_ws, size_t ws_size,
                              hipStream_t stream) {
    const float* sino  = (const float*)d_in[0];
    const float* alpha = (const float*)d_in[1];
    const float* apod  = (const float*)d_in[2];
    const int*   k0    = (const int*)d_in[3];
    const void*  valid = d_in[4];

    float*  out = (float*)d_out;
    double* wsd = (double*)d_ws;
    float*  wsf = (float*)((char*)d_ws + 4096);
    __half* S16 = (__half*)((char*)d_ws + WS_S16_OFF);
    uint4*  pk  = (uint4*)((char*)d_ws + WS_PT_OFF);
    float*  parts = (float*)((char*)d_ws + WS_PT_OFF);

    k_stats   <<<256,  256, 0, stream>>>(sino, wsd);
    k_finalize<<<1,    256, 0, stream>>>(apod, (const unsigned char*)valid, wsd, wsf);
    k_build   <<<1024, 256, 0, stream>>>(sino, wsf, S16);
    if (ws_size >= WS7_REQUIRED) {
        k_pack   <<<2048, 256, 0, stream>>>(k0, alpha, valid, wsf, pk);
        k_das7   <<<256, 1024, 0, stream>>>(pk, S16, wsf);
        k_reduce2<<<256,  256, 0, stream>>>((const __half*)pk, out);
    } else {
        k_das2  <<<2048, 1024, 0, stream>>>(k0, alpha, valid, S16, wsf, parts);
        k_reduce<<<512,   256, 0, stream>>>(parts, out);
    }
}

// Round 9
// 65.180 us; speedup vs baseline: 1.0392x; 1.0392x over previous
//
#include <hip/hip_runtime.h>
#include <hip/hip_fp16.h>

#define NB    8
#define NDET  128
#define NT    2048
#define NPIX  65536            // 256*256
#define NELEM (NDET * NT)      // 262144 per batch
#define NGRP  32               // detector groups of 4

// ws layout (bytes):
//   0       : double partials [256][2]  (sum, sumsq per reduction block)
//   4096    : float  wsf[0..7] mean, [8..15] inv_std, uint [16] valid-mode,
//             [17] 1/norm, [32..159] apodn[d]
//   8192    : __half S16[NDET][NT][NB]  (4 MiB)
//   +4M     : 32 MiB region shared in-place, TILE-MAJOR layout:
//               uint4 pk[tile=p>>6][g][px&63]   (tile stride 32KB)
//               k_pack writes it; k_das7 reads+overwrites in place with fp16
//               partials; k_reduce2 reads those.
//             (das2 fallback reuses this region as float partials[8][NB][NPIX])

#define WS_S16_OFF   8192
#define WS_PT_OFF    (8192 + (size_t)NDET * NT * NB * 2)
#define WS7_REQUIRED (WS_PT_OFF + (size_t)NGRP * NPIX * NB * 2)
#define WS2_REQUIRED (WS_PT_OFF + (size_t)8 * NB * NPIX * 4)

__global__ __launch_bounds__(256) void k_stats(const float* __restrict__ sino,
                                               double* __restrict__ wsd) {
    const int bx = blockIdx.x;            // 0..255
    const int b = bx >> 5, i = bx & 31;   // batch, chunk
    const float4* src = (const float4*)(sino + (size_t)b * NELEM);
    const int base = i * 2048;            // 2048 float4 per chunk
    double s = 0.0, ss = 0.0;
    for (int r = 0; r < 8; ++r) {
        float4 v = src[base + r * 256 + threadIdx.x];
        double d0 = v.x, d1 = v.y, d2 = v.z, d3 = v.w;
        s  += d0 + d1 + d2 + d3;
        ss += d0 * d0 + d1 * d1 + d2 * d2 + d3 * d3;
    }
    for (int off = 32; off; off >>= 1) {
        s  += __shfl_down(s, off);
        ss += __shfl_down(ss, off);
    }
    __shared__ double lds[8];
    const int wave = threadIdx.x >> 6;
    if ((threadIdx.x & 63) == 0) { lds[wave * 2] = s; lds[wave * 2 + 1] = ss; }
    __syncthreads();
    if (threadIdx.x == 0) {
        double S = 0, SS = 0;
        for (int w = 0; w < 4; ++w) { S += lds[w * 2]; SS += lds[w * 2 + 1]; }
        wsd[bx * 2] = S; wsd[bx * 2 + 1] = SS;
    }
}

__global__ __launch_bounds__(256) void k_finalize(const float* __restrict__ apod,
                                                  const unsigned char* __restrict__ validb,
                                                  const double* __restrict__ wsd,
                                                  float* __restrict__ wsf) {
    __shared__ float sap[NDET];
    __shared__ int sflag;
    const int t = threadIdx.x;
    if (t == 0) sflag = 0;
    if (t < NDET) sap[t] = apod[t];
    // Detect `valid` element width. numpy bool -> 1 byte/elem: bytes at
    // offset%4==1 are ~99% ones somewhere in 64KB. int32/f32: always 0.
    int local = 0;
    {
        const unsigned char* vb = validb + t * 256;
        for (int j = 1; j < 256; j += 4) local |= (vb[j] != 0);
    }
    __syncthreads();
    if (local) atomicOr(&sflag, 1);
    if (t < NB) {
        double S = 0, SS = 0;
        for (int i = 0; i < 32; ++i) {
            S  += wsd[(t * 32 + i) * 2];
            SS += wsd[(t * 32 + i) * 2 + 1];
        }
        double mean = S / (double)NELEM;
        double var  = SS / (double)NELEM - mean * mean;
        double istd = 1.0 / sqrt(var + (double)(1.1920928955078125e-07f));
        wsf[t]     = (float)mean;
        wsf[8 + t] = (float)istd;
    }
    if (t == 0) {
        double a = 0;
        for (int d = 0; d < NDET; ++d) a += (double)sap[d];
        float norm = fmaxf((float)a, 1.1754943508222875e-38f);
        wsf[17] = 1.0f / norm;
    }
    __syncthreads();
    if (t < NDET) wsf[32 + t] = sap[t] * wsf[17];
    if (t == 0) ((unsigned int*)wsf)[16] = (unsigned int)(sflag != 0);
}

__global__ __launch_bounds__(256) void k_build(const float* __restrict__ sino,
                                               const float* __restrict__ wsf,
                                               __half* __restrict__ S16) {
    const int dt = blockIdx.x * 256 + threadIdx.x;   // d*NT + t
    union { uint4 q; __half h[8]; } u;
#pragma unroll
    for (int b = 0; b < NB; ++b) {
        float x = sino[(size_t)b * NELEM + dt];
        u.h[b] = __float2half((x - wsf[b]) * wsf[8 + b]);
    }
    *(uint4*)(S16 + (size_t)dt * 8) = u.q;
}

// ---- pack v3: tile-major output, dense reads AND dense writes.
// Block = one 64-px tile. Phase 1: read 128KB contiguous (k0/alpha/valid for
// 64 rows), pack word = (k0 & 0x7FF) | (valid<<11) | (fp16(alpha)<<16) into
// LDS T[q][px] (row pad 65 to spread banks). Phase 2: write the 32KB tile
// contiguously: pk[tile*2048 + g*64 + px], lane-consecutive -> 4KB/wave-instr,
// single page, all channels. No 1MB-strided streams.
__global__ __launch_bounds__(256) void k_pack(const int* __restrict__ k0,
                                              const float* __restrict__ alpha,
                                              const void* __restrict__ valid,
                                              const float* __restrict__ wsf,
                                              uint4* __restrict__ packT) {
    __shared__ uint4 T[NGRP * 65];
    const unsigned int mode = ((const unsigned int*)wsf)[16];
    const int tile = blockIdx.x;           // 0..1023
    const size_t eb = (size_t)tile * 64 * NDET;   // element base
    const int t = threadIdx.x;
#pragma unroll
    for (int i = 0; i < 8; ++i) {
        const int flat = t + i * 256;      // uint4-chunk index in tile, 0..2047
        const int px = flat >> 5, q = flat & 31;
        int4   kq = *(const int4*)(k0 + eb + (size_t)flat * 4);
        float4 aq = *(const float4*)(alpha + eb + (size_t)flat * 4);
        unsigned int vb[4];
        if (mode) {
            unsigned int v = *(const unsigned int*)((const unsigned char*)valid + eb + (size_t)flat * 4);
            vb[0] = v & 0xffu; vb[1] = (v >> 8) & 0xffu;
            vb[2] = (v >> 16) & 0xffu; vb[3] = v >> 24;
        } else {
            uint4 v = *(const uint4*)((const unsigned int*)valid + eb + (size_t)flat * 4);
            vb[0] = v.x; vb[1] = v.y; vb[2] = v.z; vb[3] = v.w;
        }
        const int   ks[4] = {kq.x, kq.y, kq.z, kq.w};
        const float as[4] = {aq.x, aq.y, aq.z, aq.w};
        uint4 o;
        unsigned int* ow = (unsigned int*)&o;
#pragma unroll
        for (int j = 0; j < 4; ++j) {
            __half ha = __float2half_rn(as[j]);
            unsigned short hb = *(unsigned short*)&ha;
            ow[j] = ((unsigned int)ks[j] & 0x7FFu) | ((vb[j] ? 1u : 0u) << 11) |
                    ((unsigned int)hb << 16);
        }
        T[q * 65 + px] = o;
    }
    __syncthreads();
    uint4* dst = packT + (size_t)tile * 2048;
#pragma unroll
    for (int i = 0; i < 8; ++i) {
        const int f = t + i * 256;         // 0..2047
        const int g = f >> 6, px = f & 63;
        dst[f] = T[g * 65 + px];           // contiguous global write
    }
}

__device__ __forceinline__ float2 h2f(unsigned int w) {
    __half2 h;
    *reinterpret_cast<unsigned int*>(&h) = w;
    return __half22float2(h);
}

// ---- LDS-staged DAS v7 (tile-indexed): lane = pixel, coalesced pk load,
// in-place fp16 partial overwrite. XCD-aligned: x = blockIdx&7, g = x*4+sub.
// pk index for (g,p): (p>>6)*2048 + g*64 + (p&63); per-wave 1KB contiguous,
// per-iter stride 512KB uniform.
__global__ __launch_bounds__(1024) void k_das7(uint4* pk,            // aliased read/write
                                               const __half* __restrict__ S16,
                                               const float* __restrict__ wsf) {
    __shared__ __align__(16) __half SL[4 * NT * NB];   // 128 KiB
    const int x     = blockIdx.x & 7;
    const int sub   = (blockIdx.x >> 3) & 3;
    const int chunk = blockIdx.x >> 5;                 // 0..7
    const int g     = x * 4 + sub;                     // 0..31
    {
        const uint4* src = (const uint4*)(S16 + (size_t)g * 4 * NT * NB);
        uint4* dst = (uint4*)SL;
#pragma unroll
        for (int i = 0; i < 8; ++i)
            dst[i * 1024 + threadIdx.x] = src[i * 1024 + threadIdx.x];
    }
    __syncthreads();

    float apn[4];
#pragma unroll
    for (int j = 0; j < 4; ++j) apn[j] = wsf[32 + g * 4 + j];

    const int tid = (int)threadIdx.x;
    const size_t idx = ((size_t)(chunk * 128 + (tid >> 6))) * 2048 + g * 64 + (tid & 63);

    uint4 pkb = pk[idx];                               // iter-0 prefetch
    for (int it = 0; it < 8; ++it) {
        const uint4 pkc = pkb;
        if (it < 7) pkb = pk[idx + (size_t)(it + 1) * 32768];

        const unsigned int pw[4] = {pkc.x, pkc.y, pkc.z, pkc.w};
        float acc[NB] = {0.f, 0.f, 0.f, 0.f, 0.f, 0.f, 0.f, 0.f};
#pragma unroll
        for (int j = 0; j < 4; ++j) {
            const unsigned int wj = pw[j];
            const int kk = (int)(wj & 0x7FFu);
            unsigned short hb = (unsigned short)(wj >> 16);
            const float aa = __half2float(*(const __half*)&hb);
            const float w  = (wj & 0x800u) ? apn[j] : 0.0f;
            const float wb = w * aa;
            const float wa = w - wb;
            const uint4* s = (const uint4*)(SL + ((size_t)(j * NT + kk) << 3));
            uint4 q0 = s[0];   // tap k,   8 batches
            uint4 q1 = s[1];   // tap k+1, 8 batches
            const unsigned int w0[4] = {q0.x, q0.y, q0.z, q0.w};
            const unsigned int w1[4] = {q1.x, q1.y, q1.z, q1.w};
#pragma unroll
            for (int h = 0; h < 4; ++h) {
                float2 f0 = h2f(w0[h]);
                float2 f1 = h2f(w1[h]);
                acc[2 * h]     += wa * f0.x + wb * f1.x;
                acc[2 * h + 1] += wa * f0.y + wb * f1.y;
            }
        }
        union { uint4 q; __half2 h[4]; } o;
#pragma unroll
        for (int h = 0; h < 4; ++h)
            o.h[h] = __floats2half2_rn(acc[2 * h], acc[2 * h + 1]);
        pk[idx + (size_t)it * 32768] = o.q;            // overwrite own slot
    }
}

__global__ __launch_bounds__(256) void k_reduce2(const __half* __restrict__ pT,
                                                 float* __restrict__ out) {
    const int p = blockIdx.x * 256 + threadIdx.x;
    const int tile = p >> 6, pl = p & 63;
    const uint4* pq = (const uint4*)pT;
    float acc[NB] = {0.f, 0.f, 0.f, 0.f, 0.f, 0.f, 0.f, 0.f};
#pragma unroll
    for (int g = 0; g < NGRP; ++g) {
        union { uint4 q; __half2 h[4]; } u;
        u.q = pq[(size_t)tile * 2048 + g * 64 + pl];
#pragma unroll
        for (int h = 0; h < 4; ++h) {
            float2 f = __half22float2(u.h[h]);
            acc[2 * h]     += f.x;
            acc[2 * h + 1] += f.y;
        }
    }
#pragma unroll
    for (int b = 0; b < NB; ++b)
        out[(size_t)b * NPIX + p] = acc[b];
}

// ---- fallback: XCD-sliced L2-gather DAS (round-2 kernel) ----
__global__ __launch_bounds__(1024) void k_das2(const int* __restrict__ k0,
                                               const float* __restrict__ alpha,
                                               const void* __restrict__ valid,
                                               const __half* __restrict__ S16,
                                               const float* __restrict__ wsf,
                                               float* __restrict__ partials) {
    const int px = threadIdx.x & 255;
    const int dc = threadIdx.x >> 8;
    const int slice = blockIdx.x & 7;
    const int chunk = blockIdx.x >> 3;
    const int p  = chunk * 256 + px;
    const int d0 = slice * 16 + dc * 4;
    const unsigned int mode = ((const unsigned int*)wsf)[16];
    const float* apodn = wsf + 32;

    float acc[NB] = {0.f, 0.f, 0.f, 0.f, 0.f, 0.f, 0.f, 0.f};
    const size_t lbase = (size_t)p * NDET + d0;

    int4   k4 = *(const int4*)(k0 + lbase);
    float4 a4 = *(const float4*)(alpha + lbase);
    unsigned int vbits;
    if (mode) {
        unsigned int v4 = *(const unsigned int*)((const unsigned char*)valid + lbase);
        vbits = ((v4 & 0xffu) ? 1u : 0u) | (((v4 >> 8) & 0xffu) ? 2u : 0u) |
                (((v4 >> 16) & 0xffu) ? 4u : 0u) | ((v4 >> 24) ? 8u : 0u);
    } else {
        uint4 v4 = *(const uint4*)((const unsigned int*)valid + lbase);
        vbits = (v4.x ? 1u : 0u) | (v4.y ? 2u : 0u) | (v4.z ? 4u : 0u) | (v4.w ? 8u : 0u);
    }
    const int   kk[4] = {k4.x, k4.y, k4.z, k4.w};
    const float aa[4] = {a4.x, a4.y, a4.z, a4.w};
#pragma unroll
    for (int j = 0; j < 4; ++j) {
        const int d = d0 + j;
        const float w  = ((vbits >> j) & 1u) ? apodn[d] : 0.0f;
        const float wb = w * aa[j];
        const float wa = w - wb;
        const uint4* s = (const uint4*)(S16 + ((size_t)(d * NT + kk[j]) << 3));
        uint4 q0 = s[0];
        uint4 q1 = s[1];
        const unsigned int w0[4] = {q0.x, q0.y, q0.z, q0.w};
        const unsigned int w1[4] = {q1.x, q1.y, q1.z, q1.w};
#pragma unroll
        for (int h = 0; h < 4; ++h) {
            float2 f0 = h2f(w0[h]);
            float2 f1 = h2f(w1[h]);
            acc[2 * h]     += wa * f0.x + wb * f1.x;
            acc[2 * h + 1] += wa * f0.y + wb * f1.y;
        }
    }

    __shared__ float red[1024][9];
#pragma unroll
    for (int b = 0; b < NB; ++b) red[threadIdx.x][b] = acc[b];
    __syncthreads();
    if (dc == 0) {
#pragma unroll
        for (int b = 0; b < NB; ++b) {
            float v = red[px][b] + red[px + 256][b] + red[px + 512][b] + red[px + 768][b];
            partials[((size_t)slice * NB + b) * NPIX + p] = v;
        }
    }
}

__global__ __launch_bounds__(256) void k_reduce(const float* __restrict__ partials,
                                                float* __restrict__ out) {
    const int i = (blockIdx.x * 256 + threadIdx.x) * 4;
    float4 s = {0.f, 0.f, 0.f, 0.f};
#pragma unroll
    for (int g = 0; g < 8; ++g) {
        float4 v = *(const float4*)(partials + (size_t)g * NB * NPIX + i);
        s.x += v.x; s.y += v.y; s.z += v.z; s.w += v.w;
    }
    *(float4*)(out + i) = s;
}

extern "C" void kernel_launch(void* const* d_in, const int* in_sizes, int n_in,
                              void* d_out, int out_size, void* d_ws, size_t ws_size,
                              hipStream_t stream) {
    const float* sino  = (const float*)d_in[0];
    const float* alpha = (const float*)d_in[1];
    const float* apod  = (const float*)d_in[2];
    const int*   k0    = (const int*)d_in[3];
    const void*  valid = d_in[4];

    float*  out = (float*)d_out;
    double* wsd = (double*)d_ws;
    float*  wsf = (float*)((char*)d_ws + 4096);
    __half* S16 = (__half*)((char*)d_ws + WS_S16_OFF);
    uint4*  pk  = (uint4*)((char*)d_ws + WS_PT_OFF);
    float*  parts = (float*)((char*)d_ws + WS_PT_OFF);

    k_stats   <<<256,  256, 0, stream>>>(sino, wsd);
    k_finalize<<<1,    256, 0, stream>>>(apod, (const unsigned char*)valid, wsd, wsf);
    k_build   <<<1024, 256, 0, stream>>>(sino, wsf, S16);
    if (ws_size >= WS7_REQUIRED) {
        k_pack   <<<1024, 256, 0, stream>>>(k0, alpha, valid, wsf, pk);
        k_das7   <<<256, 1024, 0, stream>>>(pk, S16, wsf);
        k_reduce2<<<256,  256, 0, stream>>>((const __half*)pk, out);
    } else {
        k_das2  <<<2048, 1024, 0, stream>>>(k0, alpha, valid, S16, wsf, parts);
        k_reduce<<<512,   256, 0, stream>>>(parts, out);
    }
}